// Round 6
// baseline (117.097 us; speedup 1.0000x reference)
//
#include <hip/hip_runtime.h>

// VQ-VAE forward + EMA update, MI355X.
// Sizes fixed by the reference: B=64, C=D=8, H=W=64, K=512.
constexpr int Kc   = 512;
constexpr int Dc   = 8;
constexpr int HWc  = 4096;            // 64*64
constexpr int CHWc = Dc * HWc;        // 32768
constexpr int Mc   = 64 * HWc;        // 262144 vectors
constexpr int TOTALc = Mc * Dc;       // 2097152 elements of z / z_q

typedef float v2f __attribute__((ext_vector_type(2)));

// 8 replica accumulators (one per XCD via blockIdx&7) to cut atomic contention.
constexpr int REP      = 8;
constexpr int RSTRIDE  = 4616;        // 512 counts + 4096 sums + 1 loss + 7 pad
constexpr int ACC_FLOATS = REP * RSTRIDE;   // 36928 floats (~148 KB)
// d_ws float layout:
//   [0 .. ACC_FLOATS)            replica accumulators (counts | sums | loss | pad) x8
//   [ACC_FLOATS .. +512)         e_sq[k]

__global__ __launch_bounds__(256) void vq_prep(const float* __restrict__ cb,
                                               float* __restrict__ ws) {
    const int tid = blockIdx.x * 256 + threadIdx.x;
    float4* w4 = (float4*)ws;
    for (int i = tid; i < ACC_FLOATS / 4; i += gridDim.x * 256)
        w4[i] = float4{0.f, 0.f, 0.f, 0.f};
    if (blockIdx.x == 0) {
        for (int k = threadIdx.x; k < Kc; k += 256) {
            float s = 0.f;
#pragma unroll
            for (int c = 0; c < Dc; ++c) {
                const float e = cb[k * Dc + c];
                s = fmaf(e, e, s);
            }
            ws[ACC_FLOATS + k] = s;
        }
    }
}

// 1024 blocks x 512 threads; block owns 256 consecutive vectors.
// k-group g = t>>7 (2 waves) scans codes [g*128, g*128+128); each thread
// scores V=2 vectors (vl, vl+128). Inner product packed over c with
// v_pk_fma_f32 (codebook pair = the one scalar operand). 32 waves/CU.
__global__ __launch_bounds__(512, 8) void vq_main(const float* __restrict__ z,
                                                  const float* __restrict__ cb,
                                                  const float* __restrict__ esq,
                                                  float* __restrict__ ws,
                                                  float* __restrict__ zq) {
    __shared__ __align__(16) float s_counts[Kc];
    __shared__ __align__(16) float s_sums[Kc * Dc];
    __shared__ float s_mn[4][256];
    __shared__ int   s_im[4][256];
    __shared__ float s_loss;

    const int t = threadIdx.x;
    {   // vectorized LDS zeroing
        const float4 z4 = {0.f, 0.f, 0.f, 0.f};
        float4* sc4 = (float4*)s_counts;          // 128 entries
        float4* ss4 = (float4*)s_sums;            // 1024 entries
        if (t < 128) sc4[t] = z4;
        for (int i = t; i < Kc * Dc / 4; i += 512) ss4[i] = z4;
        if (t == 0) s_loss = 0.f;
    }

    const int vl = t & 127;
    // wave-uniform k-group; readfirstlane keeps codebook indices provably
    // uniform -> s_load (scalar) path for cb/esq.
    const int g  = __builtin_amdgcn_readfirstlane(t >> 7);   // 0..3
    const int k0 = g << 7;

    const int base = blockIdx.x * 256;        // 256-aligned -> one batch idx
    const int n0 = (base + vl) & (HWc - 1);
    const int b  = base >> 12;
    const float* zb = z + b * CHWc + n0;

    // zzXp[p] = -2*z for vector (vl / vl+128), packed over channel pairs.
    v2f zz0p[4], zz1p[4];
#pragma unroll
    for (int p = 0; p < 4; ++p) {
        zz0p[p].x = -2.0f * zb[(2 * p)     * HWc];       // coalesced
        zz0p[p].y = -2.0f * zb[(2 * p + 1) * HWc];
        zz1p[p].x = -2.0f * zb[(2 * p)     * HWc + 128];
        zz1p[p].y = -2.0f * zb[(2 * p + 1) * HWc + 128];
    }

    const v2f* cb2 = (const v2f*)cb;          // row k = cb2[4k..4k+3]

    // argmin over this k-group: score = e_sq[k] - 2*dot(z,e_k) (monotone-eq).
    float mn0 = 3.4e38f, mn1 = 3.4e38f;
    int   i0 = k0, i1 = k0;
#pragma unroll 4
    for (int kk = 0; kk < 128; ++kk) {
        const int k = k0 + kk;
        const v2f e0 = cb2[k * 4 + 0];        // uniform -> s_load (SGPR pair)
        const v2f e1 = cb2[k * 4 + 1];
        const v2f e2 = cb2[k * 4 + 2];
        const v2f e3 = cb2[k * 4 + 3];
        const float eq = esq[k];              // uniform -> SGPR
        v2f a0, a1;
        asm("v_pk_mul_f32 %0, %1, %2"         : "=v"(a0) : "v"(zz0p[0]), "s"(e0));
        asm("v_pk_fma_f32 %0, %1, %2, %3"     : "=v"(a0) : "v"(zz0p[1]), "s"(e1), "v"(a0));
        asm("v_pk_fma_f32 %0, %1, %2, %3"     : "=v"(a0) : "v"(zz0p[2]), "s"(e2), "v"(a0));
        asm("v_pk_fma_f32 %0, %1, %2, %3"     : "=v"(a0) : "v"(zz0p[3]), "s"(e3), "v"(a0));
        asm("v_pk_mul_f32 %0, %1, %2"         : "=v"(a1) : "v"(zz1p[0]), "s"(e0));
        asm("v_pk_fma_f32 %0, %1, %2, %3"     : "=v"(a1) : "v"(zz1p[1]), "s"(e1), "v"(a1));
        asm("v_pk_fma_f32 %0, %1, %2, %3"     : "=v"(a1) : "v"(zz1p[2]), "s"(e2), "v"(a1));
        asm("v_pk_fma_f32 %0, %1, %2, %3"     : "=v"(a1) : "v"(zz1p[3]), "s"(e3), "v"(a1));
        const float sc0 = a0.x + a0.y + eq;   // v_add3 (one SGPR)
        const float sc1 = a1.x + a1.y + eq;
        const bool c0 = sc0 < mn0;  // strict <: first index wins ties (ref)
        mn0 = c0 ? sc0 : mn0;
        i0  = c0 ? k   : i0;
        const bool c1 = sc1 < mn1;
        mn1 = c1 ? sc1 : mn1;
        i1  = c1 ? k   : i1;
    }
    s_mn[g][vl]       = mn0;
    s_im[g][vl]       = i0;
    s_mn[g][vl + 128] = mn1;
    s_im[g][vl + 128] = i1;
    __syncthreads();

    if (t < 256) {
        const int v = t;                      // block-local vector id
        float mnv = s_mn[0][v];
        int   imv = s_im[0][v];
#pragma unroll
        for (int gg = 1; gg < 4; ++gg) {
            const float m2 = s_mn[gg][v];     // groups ascending in k:
            const int   j2 = s_im[gg][v];     // strict < keeps first index
            const bool  c2 = m2 < mnv;
            mnv = c2 ? m2 : mnv;
            imv = c2 ? j2 : imv;
        }

        // Recover this thread's merge-vector z from registers:
        // t<128 -> vector vl (zz0p), t>=128 -> vector vl+128 (zz1p).
        float zr[Dc];
#pragma unroll
        for (int p = 0; p < 4; ++p) {
            const v2f zzsel = (t < 128) ? zz0p[p] : zz1p[p];
            zr[2 * p]     = -0.5f * zzsel.x;  // exact (pow2 scale)
            zr[2 * p + 1] = -0.5f * zzsel.y;
        }

        // Gather old-codebook row (16 KB table, L1-hot; 32B/lane).
        const float4* cb4 = (const float4*)cb;
        const float4 qa = cb4[imv * 2], qb = cb4[imv * 2 + 1];
        const float q[Dc] = {qa.x, qa.y, qa.z, qa.w, qb.x, qb.y, qb.z, qb.w};

        const int nv = (base + v) & (HWc - 1);
        float* zqv = zq + b * CHWc + nv;
        float lsum = 0.f;
#pragma unroll
        for (int c = 0; c < Dc; ++c) {
            zqv[c * HWc] = q[c];              // coalesced stores
            const float d = q[c] - zr[c];
            lsum = fmaf(d, d, lsum);
        }

        // Per-block LDS histogram (ds_add_f32).
        unsafeAtomicAdd(&s_counts[imv], 1.0f);
#pragma unroll
        for (int c = 0; c < Dc; ++c)
            unsafeAtomicAdd(&s_sums[imv * Dc + c], zr[c]);
        unsafeAtomicAdd(&s_loss, lsum);
    }
    __syncthreads();

    // Flush non-zero bins to this block's replica accumulator (all 512 thr).
    float* acc = ws + (blockIdx.x & (REP - 1)) * RSTRIDE;
    for (int i = t; i < Kc; i += 512) {
        const float val = s_counts[i];
        if (val != 0.f) unsafeAtomicAdd(&acc[i], val);
    }
    for (int i = t; i < Kc * Dc; i += 512) {
        const float val = s_sums[i];
        if (val != 0.f) unsafeAtomicAdd(&acc[512 + i], val);
    }
    if (t == 0) unsafeAtomicAdd(&acc[4608], s_loss);
}

__global__ __launch_bounds__(512) void vq_final(const float* __restrict__ ws,
                                                const float* __restrict__ ema_cs,
                                                const float* __restrict__ ema_w,
                                                float* __restrict__ out) {
    constexpr float DEC  = 0.99f;
    constexpr float OMD  = (float)(1.0 - 0.99);      // matches jnp f32 cast
    constexpr float EPSf = 1e-5f;
    constexpr float KEPS = (float)(512 * 1e-5);      // 0.00512
    __shared__ float red[512];
    __shared__ float s_cs[512];

    const int t = threadIdx.x;   // 512 threads, 1 block
    // counts: lane-consecutive reads per replica (coalesced)
    float cnt = 0.f;
#pragma unroll
    for (int r = 0; r < REP; ++r) cnt += ws[r * RSTRIDE + t];
    const float ncs = ema_cs[t] * DEC + cnt * OMD;
    red[t] = ncs;
    __syncthreads();
    for (int s = 256; s > 0; s >>= 1) {
        if (t < s) red[t] += red[t + s];
        __syncthreads();
    }
    const float n  = red[0];
    const float cs = (ncs + EPSf) / (n + KEPS) * n;
    s_cs[t] = cs;

    float* out_loss = out + TOTALc;          // [1]
    float* out_cb   = out + TOTALc + 1;      // [K*D]
    float* out_cs   = out_cb + Kc * Dc;      // [K]
    float* out_nw   = out_cs + Kc;           // [K*D]

    out_cs[t] = cs;
    __syncthreads();

    // sums: fully coalesced element-major passes
    for (int e = t; e < Kc * Dc; e += 512) {
        float sm = 0.f;
#pragma unroll
        for (int r = 0; r < REP; ++r) sm += ws[r * RSTRIDE + 512 + e];
        const float nw = ema_w[e] * DEC + sm * OMD;
        out_nw[e] = nw;
        out_cb[e] = nw / s_cs[e >> 3];
    }
    if (t == 0) {
        float ls = 0.f;
#pragma unroll
        for (int r = 0; r < REP; ++r) ls += ws[r * RSTRIDE + 4608];
        out_loss[0] = ls * (1.0f / 2097152.0f);  // /2^21 exact
    }
}

extern "C" void kernel_launch(void* const* d_in, const int* in_sizes, int n_in,
                              void* d_out, int out_size, void* d_ws, size_t ws_size,
                              hipStream_t stream) {
    const float* z      = (const float*)d_in[0];
    const float* cb     = (const float*)d_in[1];
    const float* ema_cs = (const float*)d_in[2];
    const float* ema_w  = (const float*)d_in[3];
    float* out = (float*)d_out;
    float* ws  = (float*)d_ws;

    vq_prep<<<32, 256, 0, stream>>>(cb, ws);
    vq_main<<<Mc / 256, 512, 0, stream>>>(z, cb, ws + ACC_FLOATS, ws, out);
    vq_final<<<1, 512, 0, stream>>>(ws, ema_cs, ema_w, out);
}